// Round 1
// baseline (123.253 us; speedup 1.0000x reference)
//
#include <hip/hip_runtime.h>
#include <math.h>

#define NN 320      // particles
#define DD 64       // dim
#define NP 1000     // permutations
#define NPAIRF ((double)(NN * (NN - 1) / 2))   // 51040

// ---------------------------------------------------------------------------
// Kernel 1: G = X * X^T  (320x320 fp32), one block per row 'a'.
// Tiny (13 MFLOP); data (80 KB) is L1/L2 resident after first touch.
// ---------------------------------------------------------------------------
__global__ __launch_bounds__(NN) void gram_kernel(const float* __restrict__ data,
                                                  float* __restrict__ G) {
    __shared__ float rowa[DD];
    const int a = blockIdx.x;
    const int t = threadIdx.x;          // 0..319, one thread per column b
    if (t < DD) rowa[t] = data[a * DD + t];
    __syncthreads();
    const float* rb = data + t * DD;
    float s = 0.f;
#pragma unroll
    for (int k = 0; k < DD; k += 4) {
        float4 x = *(const float4*)(rb + k);
        s = fmaf(rowa[k + 0], x.x, s);
        s = fmaf(rowa[k + 1], x.y, s);
        s = fmaf(rowa[k + 2], x.z, s);
        s = fmaf(rowa[k + 3], x.w, s);
    }
    G[a * NN + t] = s;
}

// ---------------------------------------------------------------------------
// Kernel 2: one block per configuration p (p=0 identity, p>=1 -> perms[p-1]).
// Iterate pairs by DATA index (a,b): G reads coalesced; slot-indexed factors
// staged in LDS. Full-matrix sweep (diagonal contributes exactly 0), halve.
// ---------------------------------------------------------------------------
__global__ __launch_bounds__(256) void perm_kernel(const float* __restrict__ G,
                                                   const int* __restrict__ types,
                                                   const int* __restrict__ perms,
                                                   const float* __restrict__ fermp,
                                                   const float* __restrict__ bosp,
                                                   float* __restrict__ out) {
    __shared__ __align__(16) float u[NN];    // sign applied to data row a
    __shared__ __align__(16) float usn[NN];  // u[a]^2 * ||x_a||^2
    __shared__ __align__(16) int   w[NN];    // type of the SLOT row a landed in
    __shared__ double rsv[4], rsv2[4];

    const int p = blockIdx.x;
    const int t = threadIdx.x;
    const float Fv = *fermp;   // -1
    const float Bv = *bosp;    // +1
    const int* prow = (p == 0) ? nullptr : (perms + (size_t)(p - 1) * NN);

    // Stage slot factors, scattered by data index a = perm[i].
    for (int i = t; i < NN; i += 256) {
        const int a  = prow ? prow[i] : i;
        const int ti = types[i];
        const int ta = types[a];
        float uv;
        if (a == i) uv = 1.0f;
        else uv = (ti == 0 && ta == 0) ? Fv : ((ti == 1 && ta == 1) ? Bv : 1.0f);
        u[a] = uv;
        w[a] = ti;
    }
    __syncthreads();
    for (int a = t; a < NN; a += 256) {
        const float g = G[a * NN + a];
        usn[a] = u[a] * u[a] * g;
    }
    __syncthreads();

    // Full-matrix pair sweep, float4 over columns. 25600 chunks / 256 thr = 100 it.
    double sv = 0.0, sv2 = 0.0;
    for (int e4 = t; e4 < NN * NN / 4; e4 += 256) {
        const int a  = e4 / (NN / 4);        // row (const-div -> magic mul)
        const int b0 = (e4 % (NN / 4)) * 4;  // first column of the chunk
        const float4 g4    = *(const float4*)(G + a * NN + b0);
        const float4 ub    = *(const float4*)(u + b0);
        const float4 usnb  = *(const float4*)(usn + b0);
        const int4   wb    = *(const int4*)(w + b0);
        const float ua = u[a], usna = usn[a];
        const int   wa = w[a];

        {   // c = 0
            const float c  = ua * ub.x;
            float d2 = fmaf(-2.0f * c, g4.x, usna + usnb.x);
            d2 = fmaxf(d2, 0.0f);
            const float d = __builtin_amdgcn_sqrtf(d2);
            const int iw = wa + wb.x;
            const float vs = (iw == 0) ? Fv : ((iw == 2) ? Bv : 1.0f);
            sv  += (double)(vs * d);
            sv2 += (double)d2;
        }
        {   // c = 1
            const float c  = ua * ub.y;
            float d2 = fmaf(-2.0f * c, g4.y, usna + usnb.y);
            d2 = fmaxf(d2, 0.0f);
            const float d = __builtin_amdgcn_sqrtf(d2);
            const int iw = wa + wb.y;
            const float vs = (iw == 0) ? Fv : ((iw == 2) ? Bv : 1.0f);
            sv  += (double)(vs * d);
            sv2 += (double)d2;
        }
        {   // c = 2
            const float c  = ua * ub.z;
            float d2 = fmaf(-2.0f * c, g4.z, usna + usnb.z);
            d2 = fmaxf(d2, 0.0f);
            const float d = __builtin_amdgcn_sqrtf(d2);
            const int iw = wa + wb.z;
            const float vs = (iw == 0) ? Fv : ((iw == 2) ? Bv : 1.0f);
            sv  += (double)(vs * d);
            sv2 += (double)d2;
        }
        {   // c = 3
            const float c  = ua * ub.w;
            float d2 = fmaf(-2.0f * c, g4.w, usna + usnb.w);
            d2 = fmaxf(d2, 0.0f);
            const float d = __builtin_amdgcn_sqrtf(d2);
            const int iw = wa + wb.w;
            const float vs = (iw == 0) ? Fv : ((iw == 2) ? Bv : 1.0f);
            sv  += (double)(vs * d);
            sv2 += (double)d2;
        }
    }

    // Reduce: wave shuffle, then cross-wave via LDS.
    for (int off = 32; off; off >>= 1) {
        sv  += __shfl_down(sv, off, 64);
        sv2 += __shfl_down(sv2, off, 64);
    }
    const int wid = t >> 6, lane = t & 63;
    if (lane == 0) { rsv[wid] = sv; rsv2[wid] = sv2; }
    __syncthreads();
    if (t == 0) {
        double SV = 0.0, SV2 = 0.0;
#pragma unroll
        for (int i = 0; i < 4; ++i) { SV += rsv[i]; SV2 += rsv2[i]; }
        SV  *= 0.5;   // ordered (a!=b) double-counts unordered pairs
        SV2 *= 0.5;
        const double var = (SV2 - SV * SV / NPAIRF) / (NPAIRF - 1.0);
        out[p] = (float)var;
    }
}

extern "C" void kernel_launch(void* const* d_in, const int* in_sizes, int n_in,
                              void* d_out, int out_size, void* d_ws, size_t ws_size,
                              hipStream_t stream) {
    const float* data  = (const float*)d_in[0];
    const float* fermp = (const float*)d_in[1];
    const float* bosp  = (const float*)d_in[2];
    const int*   types = (const int*)d_in[3];
    const int*   perms = (const int*)d_in[4];
    float* out = (float*)d_out;
    float* G   = (float*)d_ws;   // 320*320*4 = 409600 B

    gram_kernel<<<NN, NN, 0, stream>>>(data, G);
    perm_kernel<<<NP + 1, 256, 0, stream>>>(G, types, perms, fermp, bosp, out);
}

// Round 2
// 96.887 us; speedup vs baseline: 1.2721x; 1.2721x over previous
//
#include <hip/hip_runtime.h>
#include <math.h>

#define NN 320      // particles
#define DD 64       // dim
#define NPAIRF ((double)(NN * (NN - 1) / 2))   // 51040

// ---------------------------------------------------------------------------
// Kernel 1: G = X * X^T (320x320 fp32). Tiny; L2-resident.
// ---------------------------------------------------------------------------
__global__ __launch_bounds__(NN) void gram_kernel(const float* __restrict__ data,
                                                  float* __restrict__ G) {
    __shared__ float rowa[DD];
    const int a = blockIdx.x;
    const int t = threadIdx.x;
    if (t < DD) rowa[t] = data[a * DD + t];
    __syncthreads();
    const float* rb = data + t * DD;
    float s = 0.f;
#pragma unroll
    for (int k = 0; k < DD; k += 4) {
        float4 x = *(const float4*)(rb + k);
        s = fmaf(rowa[k + 0], x.x, s);
        s = fmaf(rowa[k + 1], x.y, s);
        s = fmaf(rowa[k + 2], x.z, s);
        s = fmaf(rowa[k + 3], x.w, s);
    }
    G[a * NN + t] = s;
}

// ---------------------------------------------------------------------------
// Kernel 2: one block per configuration. Threads own FIXED columns (4 each,
// cached in VGPRs); loop sweeps rows 3-at-a-time. Row quantities come from
// one broadcast ds_read_b128 per iteration. Full-matrix sweep (diagonal
// contributes ~0), halve at the end.
// ---------------------------------------------------------------------------
__global__ __launch_bounds__(256) void perm_kernel(const float* __restrict__ G,
                                                   const int* __restrict__ types,
                                                   const int* __restrict__ perms,
                                                   const float* __restrict__ fermp,
                                                   const float* __restrict__ bosp,
                                                   float* __restrict__ out) {
    __shared__ __align__(16) float apk[NN * 4];   // per-row: {u, usn, -2u, w}
    __shared__ __align__(16) float colu[NN];      // u_b
    __shared__ __align__(16) float colusn[NN];    // usn_b
    __shared__ __align__(16) float colvF[NN];     // (w_b==0) ? Fv : 1
    __shared__ __align__(16) float colvB[NN];     // (w_b==1) ? Bv : 1
    __shared__ double rsv[4], rsv2[4];

    const int p = blockIdx.x;
    const int t = threadIdx.x;
    const float Fv = *fermp;
    const float Bv = *bosp;
    const int* prow = (p == 0) ? (const int*)nullptr : perms + (size_t)(p - 1) * NN;

    // Stage per-data-index quantities (scatter by a = perm[i]).
    for (int i = t; i < NN; i += 256) {
        const int a  = prow ? prow[i] : i;
        const int ti = types[i];
        const int ta = types[a];
        float uv = 1.0f;
        if (a != i) uv = (ti == 0 && ta == 0) ? Fv : ((ti == 1 && ta == 1) ? Bv : 1.0f);
        colu[a]  = uv;
        colvF[a] = (ti == 0) ? Fv : 1.0f;
        colvB[a] = (ti == 1) ? Bv : 1.0f;
        apk[4 * a + 0] = uv;
        apk[4 * a + 2] = -2.0f * uv;
        apk[4 * a + 3] = (float)ti;
    }
    __syncthreads();
    for (int a = t; a < NN; a += 256) {
        const float uv  = colu[a];
        const float usn = uv * uv * G[a * NN + a];
        colusn[a] = usn;
        apk[4 * a + 1] = usn;
    }
    __syncthreads();

    float accv = 0.0f, acc2 = 0.0f;

    if (t < 240) {
        const int rowoff = t / 80;           // 0..2
        const int col0   = (t % 80) * 4;     // fixed 4-column strip
        // Column-side quantities: resident in VGPRs for the whole sweep.
        const float4 ub   = *(const float4*)(colu   + col0);
        const float4 usnb = *(const float4*)(colusn + col0);
        const float4 vFb  = *(const float4*)(colvF  + col0);
        const float4 vBb  = *(const float4*)(colvB  + col0);

        const float* gp  = G + rowoff * NN + col0;   // advances 3 rows/iter
        const float* app = apk + 4 * rowoff;         // row pack, advances 12/iter

#define PAIR_BODY(GC, UBC, USNBC, VFC, VBC)                      \
        {                                                        \
            const float tt  = (UBC) * (GC);                      \
            const float sab = ap.y + (USNBC);                    \
            float d2 = fmaf(ap.z, tt, sab);                      \
            d2 = fmaxf(d2, 0.0f);                                \
            const float dd = __builtin_amdgcn_sqrtf(d2);         \
            const float vsl = wa1 ? (VBC) : (VFC);               \
            accv = fmaf(vsl, dd, accv);                          \
            acc2 += d2;                                          \
        }

#define ROW_BODY()                                               \
        {                                                        \
            const float4 ap = *(const float4*)app;               \
            const bool wa1 = (ap.w != 0.0f);                     \
            const float4 g4 = *(const float4*)gp;                \
            PAIR_BODY(g4.x, ub.x, usnb.x, vFb.x, vBb.x)          \
            PAIR_BODY(g4.y, ub.y, usnb.y, vFb.y, vBb.y)          \
            PAIR_BODY(g4.z, ub.z, usnb.z, vFb.z, vBb.z)          \
            PAIR_BODY(g4.w, ub.w, usnb.w, vFb.w, vBb.w)          \
        }

        // 106 full iterations cover rows 0..317 (3 rows/iter).
        for (int it = 0; it < 106; ++it) {
            ROW_BODY();
            gp  += 3 * NN;
            app += 12;
        }
        // Epilogue: rows 318, 319 (rowoff 0 and 1 only).
        if (rowoff < 2) {
            ROW_BODY();
        }
#undef ROW_BODY
#undef PAIR_BODY
    }

    // Reduce: f32 lane accumulators -> f64, wave shuffle, cross-wave via LDS.
    double sv = (double)accv, sv2 = (double)acc2;
    for (int off = 32; off; off >>= 1) {
        sv  += __shfl_down(sv, off, 64);
        sv2 += __shfl_down(sv2, off, 64);
    }
    const int wid = t >> 6, lane = t & 63;
    if (lane == 0) { rsv[wid] = sv; rsv2[wid] = sv2; }
    __syncthreads();
    if (t == 0) {
        double SV = 0.0, SV2 = 0.0;
#pragma unroll
        for (int i = 0; i < 4; ++i) { SV += rsv[i]; SV2 += rsv2[i]; }
        SV  *= 0.5;   // ordered full-matrix sweep double-counts unordered pairs
        SV2 *= 0.5;
        const double var = (SV2 - SV * SV / NPAIRF) / (NPAIRF - 1.0);
        out[p] = (float)var;
    }
}

extern "C" void kernel_launch(void* const* d_in, const int* in_sizes, int n_in,
                              void* d_out, int out_size, void* d_ws, size_t ws_size,
                              hipStream_t stream) {
    const float* data  = (const float*)d_in[0];
    const float* fermp = (const float*)d_in[1];
    const float* bosp  = (const float*)d_in[2];
    const int*   types = (const int*)d_in[3];
    const int*   perms = (const int*)d_in[4];
    float* out = (float*)d_out;
    float* G   = (float*)d_ws;   // 320*320*4 = 409600 B

    gram_kernel<<<NN, NN, 0, stream>>>(data, G);
    perm_kernel<<<1000 + 1, 256, 0, stream>>>(G, types, perms, fermp, bosp, out);
}

// Round 3
// 95.761 us; speedup vs baseline: 1.2871x; 1.0118x over previous
//
#include <hip/hip_runtime.h>
#include <math.h>

#define NN 320      // particles
#define DD 64       // dim
#define NPAIRF ((double)(NN * (NN - 1) / 2))   // 51040

// ---------------------------------------------------------------------------
// Kernel 1: G = X * X^T (320x320 fp32). Tiny; L2-resident.
// ---------------------------------------------------------------------------
__global__ __launch_bounds__(NN) void gram_kernel(const float* __restrict__ data,
                                                  float* __restrict__ G) {
    __shared__ float rowa[DD];
    const int a = blockIdx.x;
    const int t = threadIdx.x;
    if (t < DD) rowa[t] = data[a * DD + t];
    __syncthreads();
    const float* rb = data + t * DD;
    float s = 0.f;
#pragma unroll
    for (int k = 0; k < DD; k += 4) {
        float4 x = *(const float4*)(rb + k);
        s = fmaf(rowa[k + 0], x.x, s);
        s = fmaf(rowa[k + 1], x.y, s);
        s = fmaf(rowa[k + 2], x.z, s);
        s = fmaf(rowa[k + 3], x.w, s);
    }
    G[a * NN + t] = s;
}

// ---------------------------------------------------------------------------
// Kernel 2: one block (512 thr, 8 waves) per configuration.
// 480 active threads = 40 column-strips (8 cols, cached in VGPRs) x 12 row
// offsets. 26 iterations x 12 rows + epilogue covers all 320 rows.
// Per row-iter/thread: 1 ds_read_b128 (row pack) + 2 global float4 (G, L2-hot)
// + 8x{mul, add, fma, sqrt|abs|, cndmask, fma-acc, add-acc|abs|}.
// Full-matrix sweep (diagonal exactly 0 since u=+-1), halve at the end.
// ---------------------------------------------------------------------------
__global__ __launch_bounds__(512, 8) void perm_kernel(const float* __restrict__ G,
                                                      const int* __restrict__ types,
                                                      const int* __restrict__ perms,
                                                      const float* __restrict__ fermp,
                                                      const float* __restrict__ bosp,
                                                      float* __restrict__ out) {
    __shared__ __align__(16) float apk[NN * 4];   // per-row: {u, usn, -2u, w}
    __shared__ __align__(16) float colu[NN];      // u_b
    __shared__ __align__(16) float colusn[NN];    // usn_b
    __shared__ __align__(16) float colvF[NN];     // (w_b==0) ? Fv : 1
    __shared__ __align__(16) float colvB[NN];     // (w_b==1) ? Bv : 1
    __shared__ double rsv[8], rsv2[8];

    const int p = blockIdx.x;
    const int t = threadIdx.x;
    const float Fv = *fermp;
    const float Bv = *bosp;
    const int* prow = (p == 0) ? (const int*)nullptr : perms + (size_t)(p - 1) * NN;

    // Stage per-data-index quantities (scatter by a = perm[i]).
    for (int i = t; i < NN; i += 512) {
        const int a  = prow ? prow[i] : i;
        const int ti = types[i];
        const int ta = types[a];
        float uv = 1.0f;
        if (a != i) uv = (ti == 0 && ta == 0) ? Fv : ((ti == 1 && ta == 1) ? Bv : 1.0f);
        colu[a]  = uv;
        colvF[a] = (ti == 0) ? Fv : 1.0f;
        colvB[a] = (ti == 1) ? Bv : 1.0f;
        apk[4 * a + 0] = uv;
        apk[4 * a + 2] = -2.0f * uv;
        apk[4 * a + 3] = (float)ti;
    }
    __syncthreads();
    for (int a = t; a < NN; a += 512) {
        const float uv  = colu[a];
        const float usn = uv * uv * G[a * NN + a];
        colusn[a] = usn;
        apk[4 * a + 1] = usn;
    }
    __syncthreads();

    float accv = 0.0f, acc2 = 0.0f;

    const int strip  = t % 40;        // 8-column strip index
    const int rowoff = t / 40;        // 0..12 (12 -> idle)

    if (rowoff < 12) {
        const int col0 = strip * 8;
        // Column-side quantities: VGPR-resident for the whole sweep.
        const float4 ub0   = *(const float4*)(colu   + col0);
        const float4 ub1   = *(const float4*)(colu   + col0 + 4);
        const float4 usnb0 = *(const float4*)(colusn + col0);
        const float4 usnb1 = *(const float4*)(colusn + col0 + 4);
        const float4 vFb0  = *(const float4*)(colvF  + col0);
        const float4 vFb1  = *(const float4*)(colvF  + col0 + 4);
        const float4 vBb0  = *(const float4*)(colvB  + col0);
        const float4 vBb1  = *(const float4*)(colvB  + col0 + 4);

        const float* gp  = G + rowoff * NN + col0;   // advances 12 rows/iter
        const float* app = apk + 4 * rowoff;         // row pack, 48 floats/iter

#define PAIR_BODY(GC, UBC, USNBC, VFC, VBC)                      \
        {                                                        \
            const float tt  = (UBC) * (GC);                      \
            const float sab = ap.y + (USNBC);                    \
            const float d2  = fmaf(ap.z, tt, sab);               \
            const float dd  = __builtin_amdgcn_sqrtf(fabsf(d2)); \
            const float vsl = wa1 ? (VBC) : (VFC);               \
            accv = fmaf(vsl, dd, accv);                          \
            acc2 += fabsf(d2);                                   \
        }

#define ROW_BODY()                                               \
        {                                                        \
            const float4 ap = *(const float4*)app;               \
            const bool wa1 = (ap.w != 0.0f);                     \
            const float4 g0 = *(const float4*)gp;                \
            const float4 g1 = *(const float4*)(gp + 4);          \
            PAIR_BODY(g0.x, ub0.x, usnb0.x, vFb0.x, vBb0.x)      \
            PAIR_BODY(g0.y, ub0.y, usnb0.y, vFb0.y, vBb0.y)      \
            PAIR_BODY(g0.z, ub0.z, usnb0.z, vFb0.z, vBb0.z)      \
            PAIR_BODY(g0.w, ub0.w, usnb0.w, vFb0.w, vBb0.w)      \
            PAIR_BODY(g1.x, ub1.x, usnb1.x, vFb1.x, vBb1.x)      \
            PAIR_BODY(g1.y, ub1.y, usnb1.y, vFb1.y, vBb1.y)      \
            PAIR_BODY(g1.z, ub1.z, usnb1.z, vFb1.z, vBb1.z)      \
            PAIR_BODY(g1.w, ub1.w, usnb1.w, vFb1.w, vBb1.w)      \
        }

        // 26 iterations x 12 rows cover rows 0..311.
#pragma unroll 2
        for (int it = 0; it < 26; ++it) {
            ROW_BODY();
            gp  += 12 * NN;
            app += 48;
        }
        // Epilogue: rows 312..319 (rowoff 0..7).
        if (rowoff < 8) {
            ROW_BODY();
        }
#undef ROW_BODY
#undef PAIR_BODY
    }

    // Reduce: f32 lane accumulators -> f64, wave shuffle, cross-wave via LDS.
    double sv = (double)accv, sv2 = (double)acc2;
    for (int off = 32; off; off >>= 1) {
        sv  += __shfl_down(sv, off, 64);
        sv2 += __shfl_down(sv2, off, 64);
    }
    const int wid = t >> 6, lane = t & 63;
    if (lane == 0) { rsv[wid] = sv; rsv2[wid] = sv2; }
    __syncthreads();
    if (t == 0) {
        double SV = 0.0, SV2 = 0.0;
#pragma unroll
        for (int i = 0; i < 8; ++i) { SV += rsv[i]; SV2 += rsv2[i]; }
        SV  *= 0.5;   // ordered full-matrix sweep double-counts unordered pairs
        SV2 *= 0.5;
        const double var = (SV2 - SV * SV / NPAIRF) / (NPAIRF - 1.0);
        out[p] = (float)var;
    }
}

extern "C" void kernel_launch(void* const* d_in, const int* in_sizes, int n_in,
                              void* d_out, int out_size, void* d_ws, size_t ws_size,
                              hipStream_t stream) {
    const float* data  = (const float*)d_in[0];
    const float* fermp = (const float*)d_in[1];
    const float* bosp  = (const float*)d_in[2];
    const int*   types = (const int*)d_in[3];
    const int*   perms = (const int*)d_in[4];
    float* out = (float*)d_out;
    float* G   = (float*)d_ws;   // 320*320*4 = 409600 B

    gram_kernel<<<NN, NN, 0, stream>>>(data, G);
    perm_kernel<<<1000 + 1, 512, 0, stream>>>(G, types, perms, fermp, bosp, out);
}